// Round 14
// baseline (9971.133 us; speedup 1.0000x reference)
//
#include <hip/hip_runtime.h>

typedef unsigned short u16;
typedef __bf16 bf16x8 __attribute__((ext_vector_type(8)));
typedef float f32x4 __attribute__((ext_vector_type(4)));
typedef float f4 __attribute__((ext_vector_type(4)));
typedef unsigned short u16x8 __attribute__((ext_vector_type(8)));
typedef unsigned short u16x4 __attribute__((ext_vector_type(4)));

#define BB 1024
#define SS 256
#define DD 300
#define HH 150
#define GG 600
#define VV 21257
#define VPAD 21376      // 167*128
#define KSTR 320        // padded K stride for h1 / emb table
#define GSTR 600        // gate row stride (u16), layout [jj][4 gates] interleaved
#define WK 160          // padded Whh K stride
#define L2E 1.442695041f
#define L2E2 2.885390082f

static __device__ __forceinline__ float bf2f(u16 u){
  unsigned v = ((unsigned)u) << 16;
  return __builtin_bit_cast(float, v);
}
static __device__ __forceinline__ u16 f2bf(float f){
  unsigned u = __builtin_bit_cast(unsigned, f);
  u = u + 0x7FFFu + ((u >> 16) & 1u);
  return (u16)(u >> 16);
}
// inputs PRE-SCALED by log2e (sig) / 2log2e (tanh)
static __device__ __forceinline__ float fsig2(float p){
  return __builtin_amdgcn_rcpf(1.0f + __builtin_amdgcn_exp2f(-p));
}
static __device__ __forceinline__ float ftanh2(float p){
  return 2.0f * __builtin_amdgcn_rcpf(1.0f + __builtin_amdgcn_exp2f(-p)) - 1.0f;
}

// ---------------- lengths from mask ----------------
__global__ void k_len(const int* __restrict__ mask, int* __restrict__ len){
  __shared__ int red[256];
  int b = blockIdx.x, t = threadIdx.x;
  red[t] = (mask[b*SS + t] != 0) ? 1 : 0;
  __syncthreads();
  for (int o = 128; o > 0; o >>= 1){
    if (t < o) red[t] += red[t+o];
    __syncthreads();
  }
  if (t == 0) len[b] = red[0];
}

// ---------------- deterministic rank sort by length (ascending) ----------------
__global__ void k_sort(const int* __restrict__ len, int* __restrict__ perm){
  __shared__ int L[1024];
  int b = threadIdx.x;
  int l = len[b];
  L[b] = l;
  __syncthreads();
  int r = 0;
  for (int j = 0; j < 1024; ++j){
    int lj = L[j];
    r += (lj < l) || (lj == l && j < b);
  }
  perm[r] = b;
}

// ---------------- weight pad/convert f32 -> bf16, gate-row pre-scale by log2e ----------------
struct PrepW {
  const float* src[8];
  u16* dst[8];
  int R[8], C[8], DR[8], DC[8];
};
__global__ void k_prepw(PrepW p){
  int z = blockIdx.y;
  int n = p.DR[z]*p.DC[z];
  for (int i = blockIdx.x*256 + threadIdx.x; i < n; i += 800*256){
    int r = i / p.DC[z], c = i - r*p.DC[z];
    float v = (r < p.R[z] && c < p.C[z]) ? p.src[z][r*p.C[z] + c] : 0.f;
    float sc = (r >= 300 && r < 450) ? L2E2 : L2E;   // g-gate rows get 2*log2e
    p.dst[z][i] = f2bf(v * sc);
  }
}
struct PrepB { const float* src[4]; float* dst[4]; };
__global__ void k_prepb(PrepB p){
  int z = blockIdx.y;
  int i = blockIdx.x*256 + threadIdx.x;
  if (i < 640){
    float v = (i < GG) ? p.src[z][i] : 0.f;
    float sc = (i >= 300 && i < 450) ? L2E2 : L2E;
    p.dst[z][i] = v * sc;
  }
}

// ---------------- embedding table pad/convert: [VPAD][KSTR] bf16, row 0 zeroed ----------------
__global__ void k_prepemb(const float* __restrict__ emb, u16* __restrict__ dst){
  long i = (long)blockIdx.x*256 + threadIdx.x;
  if (i >= (long)VPAD*KSTR) return;
  int r = (int)(i / KSTR), c = (int)(i - (long)r*KSTR);
  float v = (r >= 1 && r < VV && c < DD) ? emb[(size_t)r*DD + c] : 0.f;
  dst[i] = f2bf(v);
}

// ---------------- big GEMM (Round-6 LDS-staged, reg-dbuf): proven-fastest total ----------------
__launch_bounds__(512, 2)
__global__ void k_gemm(const u16* __restrict__ A,
                       const u16* __restrict__ Wf, const u16* __restrict__ Wb,
                       const float* __restrict__ bsf, const float* __restrict__ bsb,
                       u16* __restrict__ of, u16* __restrict__ ob)
{
  const u16* W = blockIdx.z ? Wb : Wf;
  const float* bias = blockIdx.z ? bsb : bsf;
  u16* outp = blockIdx.z ? ob : of;

  __shared__ u16 Al[128*40];
  __shared__ u16 Bl[320*40];

  int tid = threadIdx.x;
  int l = tid & 63, w = tid >> 6;
  int lo = l & 15, hi = l >> 4;
  int wm = w >> 2, wn = w & 3;
  int m0 = blockIdx.x * 128;
  int n0 = blockIdx.y * 320;

  int ar = tid >> 2, ac = (tid & 3) * 8;
  const u16* Arow = A + (size_t)(m0 + ar)*KSTR + ac;
  bool bvld[3]; int brr[3], bcc[3];
  const u16* Brow[3];
  #pragma unroll
  for (int i = 0; i < 3; ++i){
    int ch = tid + i*512;
    bvld[i] = (ch < 1280);
    int r2 = bvld[i] ? (ch >> 2) : 0;
    brr[i] = r2; bcc[i] = (ch & 3) * 8;
    Brow[i] = W + (size_t)(n0 + r2)*KSTR + bcc[i];
  }

  u16x8 ra = *(const u16x8*)Arow;
  u16x8 rbv[3];
  #pragma unroll
  for (int i = 0; i < 3; ++i) if (bvld[i]) rbv[i] = *(const u16x8*)Brow[i];

  f32x4 acc[4][5];
  #pragma unroll
  for (int a = 0; a < 4; ++a)
    #pragma unroll
    for (int b = 0; b < 5; ++b) acc[a][b] = (f32x4){0.f,0.f,0.f,0.f};

  for (int kk = 0; kk < 10; ++kk){
    __syncthreads();
    *(u16x8*)&Al[ar*40 + ac] = ra;
    #pragma unroll
    for (int i = 0; i < 3; ++i)
      if (bvld[i]) *(u16x8*)&Bl[brr[i]*40 + bcc[i]] = rbv[i];
    __syncthreads();
    if (kk < 9){
      int k1 = (kk+1)*32;
      ra = *(const u16x8*)(Arow + k1);
      #pragma unroll
      for (int i = 0; i < 3; ++i)
        if (bvld[i]) rbv[i] = *(const u16x8*)(Brow[i] + k1);
    }
    u16x8 av[4], bv[5];
    #pragma unroll
    for (int mt = 0; mt < 4; ++mt)
      av[mt] = *(const u16x8*)&Al[(wm*64 + mt*16 + lo)*40 + hi*8];
    #pragma unroll
    for (int nt = 0; nt < 5; ++nt)
      bv[nt] = *(const u16x8*)&Bl[(wn*80 + nt*16 + lo)*40 + hi*8];
    #pragma unroll
    for (int mt = 0; mt < 4; ++mt)
      #pragma unroll
      for (int nt = 0; nt < 5; ++nt)
        acc[mt][nt] = __builtin_amdgcn_mfma_f32_16x16x32_bf16(
            __builtin_bit_cast(bf16x8, av[mt]),
            __builtin_bit_cast(bf16x8, bv[nt]),
            acc[mt][nt], 0, 0, 0);
  }

  #pragma unroll
  for (int mt = 0; mt < 4; ++mt){
    #pragma unroll
    for (int nt = 0; nt < 5; ++nt){
      int col = n0 + wn*80 + nt*16 + lo;
      if (col < GG){
        float bsv = bias[col];
        int g = (col >= 450) ? 3 : (col >= 300) ? 2 : (col >= 150) ? 1 : 0;
        int cofs = (col - g*150)*4 + g;   // interleaved [jj][gate]
        #pragma unroll
        for (int r = 0; r < 4; ++r){
          int row = m0 + wm*64 + mt*16 + hi*4 + r;
          outp[(size_t)row*GSTR + cofs] = f2bf(acc[mt][nt][r] + bsv);
        }
      }
    }
  }
}

// ---------------- merged recurrence (R13 structure, unchanged) ----------------
#define PREF(GB, TT)                                                            \
  {                                                                             \
    _Pragma("unroll")                                                           \
    for (int r = 0; r < 4; ++r){                                                \
      int Li = Lr[r];                                                           \
      int tt = ((TT) < Li) ? (TT) : (Li-1);                                     \
      int s_ = dir ? (Li-1-tt) : tt;                                            \
      int rowi;                                                                 \
      if (isL1) rowi = rowb[r] + s_;                                            \
      else      rowi = (int)tks[(hi*4+r)*256 + s_];                             \
      GB[r] = *(const u16x4*)(xg + (size_t)rowi*GSTR + jjc*4);                  \
    }                                                                           \
  }

#define REC_STEP(T, PB, GB)                                                     \
  {                                                                             \
    f32x4 acc0 = {0,0,0,0}, acc1 = {0,0,0,0}, acc2 = {0,0,0,0}, acc3 = {0,0,0,0}; \
    _Pragma("unroll")                                                           \
    for (int ks = 0; ks < 5; ++ks){                                             \
      u16x8 a_ = *(const u16x8*)&hsm[PB][lo*168 + ks*32 + hi*8];                \
      acc0 = __builtin_amdgcn_mfma_f32_16x16x32_bf16(                           \
          __builtin_bit_cast(bf16x8, a_), __builtin_bit_cast(bf16x8, bw[0][ks]), acc0, 0,0,0); \
      acc1 = __builtin_amdgcn_mfma_f32_16x16x32_bf16(                           \
          __builtin_bit_cast(bf16x8, a_), __builtin_bit_cast(bf16x8, bw[1][ks]), acc1, 0,0,0); \
      acc2 = __builtin_amdgcn_mfma_f32_16x16x32_bf16(                           \
          __builtin_bit_cast(bf16x8, a_), __builtin_bit_cast(bf16x8, bw[2][ks]), acc2, 0,0,0); \
      acc3 = __builtin_amdgcn_mfma_f32_16x16x32_bf16(                           \
          __builtin_bit_cast(bf16x8, a_), __builtin_bit_cast(bf16x8, bw[3][ks]), acc3, 0,0,0); \
    }                                                                           \
    _Pragma("unroll")                                                           \
    for (int r = 0; r < 4; ++r){                                                \
      if (jv && (T) < Lr[r]){                                                   \
        float pi  = acc0[r] + bf2f(GB[r][0]);                                   \
        float pf  = acc1[r] + bf2f(GB[r][1]);                                   \
        float pgv = acc2[r] + bf2f(GB[r][2]);                                   \
        float po  = acc3[r] + bf2f(GB[r][3]);                                   \
        float ig = fsig2(pi), fg = fsig2(pf), g2 = ftanh2(pgv), og = fsig2(po); \
        float cc = fg*cst[r] + ig*g2;  cst[r] = cc;                             \
        float hn = og * ftanh2(L2E2 * cc);                                      \
        u16 hb = f2bf(hn);                                                      \
        hsm[(PB)^1][(hi*4+r)*168 + jj] = hb;                                    \
        if (!isL1){                                                             \
          int s_ = dir ? (Lr[r]-1-(T)) : (T);                                   \
          h1[(size_t)(rowb[r]+s_)*KSTR + dir*150 + jj] = hb;                    \
        } else {                                                                \
          bool isl = dir ? ((T)==0) : ((T)==Lr[r]-1);                           \
          if (isl) lastf[(size_t)bo2[r]*304 + dir*150 + jj] = hn;               \
        }                                                                       \
      }                                                                         \
    }                                                                           \
    if ((T)+4 < maxL){                                                          \
      PREF(GB, (T)+4)                                                           \
    }                                                                           \
    __builtin_amdgcn_sched_barrier(0);                                          \
    asm volatile("s_waitcnt lgkmcnt(0)");                                       \
    __builtin_amdgcn_sched_barrier(0);                                          \
    __builtin_amdgcn_s_barrier();                                               \
    __builtin_amdgcn_sched_barrier(0);                                          \
  }

__launch_bounds__(640, 2)
__global__ void k_recM(const u16* __restrict__ gF, const u16* __restrict__ gBf,
                       const u16* __restrict__ tF, const u16* __restrict__ tB,
                       const u16* __restrict__ Wh0F, const u16* __restrict__ Wh0B,
                       const u16* __restrict__ Wh1F, const u16* __restrict__ Wh1B,
                       const int* __restrict__ len, const int* __restrict__ perm,
                       const int* __restrict__ x,
                       u16* __restrict__ h1, float* __restrict__ lastf,
                       int coA, int coB, int mode0)
{
  const int isL1 = (blockIdx.z == 0) ? mode0 : 0;
  const int dir  = blockIdx.y;
  const int tile = blockIdx.x;
  const int co   = isL1 ? coA : coB;
  const u16* xg  = isL1 ? (dir ? gBf : gF) : (dir ? tB : tF);
  const u16* Whh = isL1 ? (dir ? Wh1B : Wh1F) : (dir ? Wh0B : Wh0F);

  __shared__ u16 hsm[2][16*168];
  __shared__ u16 tks[16*256];
  __shared__ int Ls[16], rbL[16], boS[16];

  int tid = threadIdx.x;
  int l = tid & 63, w = tid >> 6;
  int lo = l & 15, hi = l >> 4;
  int jj = w*16 + lo;
  bool jv = (jj < HH);
  int jjc = jv ? jj : 0;

  u16x8 bw[4][5];
  #pragma unroll
  for (int g = 0; g < 4; ++g)
    #pragma unroll
    for (int ks = 0; ks < 5; ++ks)
      bw[g][ks] = *(const u16x8*)(Whh + (size_t)(g*150 + jj)*WK + ks*32 + hi*8);

  for (int i = tid; i < 2*16*168; i += 640) ((u16*)hsm)[i] = 0;
  if (tid < 16){
    int b = perm[co + tile*16 + tid];
    Ls[tid]  = len[b];
    rbL[tid] = (tile*16 + tid)*SS;
    boS[tid] = b;
  }
  __syncthreads();
  if (!isL1){
    for (int idx = tid; idx < 16*256; idx += 640){
      int i = idx >> 8, s = idx & 255;
      tks[idx] = (u16)x[boS[i]*SS + s];
    }
  }
  __syncthreads();

  int maxL = Ls[15];
  int Lr[4], rowb[4], bo2[4];
  #pragma unroll
  for (int r = 0; r < 4; ++r){
    int i = hi*4 + r;
    Lr[r] = Ls[i]; rowb[r] = rbL[i]; bo2[r] = boS[i];
  }

  float cst[4] = {0.f, 0.f, 0.f, 0.f};
  u16x4 g0[4], g1[4], g2b[4], g3[4];
  PREF(g0, 0)
  PREF(g1, 1)
  PREF(g2b, 2)
  PREF(g3, 3)

  for (int t = 0; t < maxL; t += 4){
    REC_STEP(t, 0, g0)
    if (t + 1 < maxL) REC_STEP(t+1, 1, g1)
    if (t + 2 < maxL) REC_STEP(t+2, 0, g2b)
    if (t + 3 < maxL) REC_STEP(t+3, 1, g3)
  }
}

// ---------------- quantitative probes: 1024 steps, 5 modes, ALL land in top-5 ----------------
// MODE bits: 1=MFMA, 2=gate-loads, 4=trans, 8=barrier, 16=h1-stores
#define PPREF(GB, TT)                                                           \
  { _Pragma("unroll")                                                           \
    for (int r = 0; r < 4; ++r){                                                \
      int s_ = (TT) & 255;                                                      \
      GB[r] = *(const u16x4*)(xg + (size_t)(prow[r]+s_)*GSTR + jjc*4);          \
    } }

#define PSTEP(T, PB, GB)                                                        \
  { f32x4 a0={0,0,0,0},a1={0,0,0,0},a2={0,0,0,0},a3={0,0,0,0};                  \
    if (MODE & 1){                                                              \
      _Pragma("unroll")                                                         \
      for (int ks = 0; ks < 5; ++ks){                                           \
        u16x8 a_ = *(const u16x8*)&hsm[PB][lo*168 + ks*32 + hi*8];              \
        a0 = __builtin_amdgcn_mfma_f32_16x16x32_bf16(                           \
            __builtin_bit_cast(bf16x8,a_), __builtin_bit_cast(bf16x8,bw[0][ks]), a0,0,0,0); \
        a1 = __builtin_amdgcn_mfma_f32_16x16x32_bf16(                           \
            __builtin_bit_cast(bf16x8,a_), __builtin_bit_cast(bf16x8,bw[1][ks]), a1,0,0,0); \
        a2 = __builtin_amdgcn_mfma_f32_16x16x32_bf16(                           \
            __builtin_bit_cast(bf16x8,a_), __builtin_bit_cast(bf16x8,bw[2][ks]), a2,0,0,0); \
        a3 = __builtin_amdgcn_mfma_f32_16x16x32_bf16(                           \
            __builtin_bit_cast(bf16x8,a_), __builtin_bit_cast(bf16x8,bw[3][ks]), a3,0,0,0); \
      }                                                                         \
    } else {                                                                    \
      _Pragma("unroll")                                                         \
      for (int ks = 0; ks < 5; ++ks){                                           \
        u16x8 a_ = *(const u16x8*)&hsm[PB][lo*168 + ks*32 + hi*8];              \
        asm volatile("" :: "v"(a_));                                            \
      }                                                                         \
      a0[0]=cst[0]; a0[1]=cst[1]; a0[2]=cst[2]; a0[3]=cst[3];                   \
      a1 = a0; a2 = a0; a3 = a0;                                                \
    }                                                                           \
    _Pragma("unroll")                                                           \
    for (int r = 0; r < 4; ++r){                                                \
      if (jv){                                                                  \
        float pi  = a0[r] + bf2f(GB[r][0]);                                     \
        float pf  = a1[r] + bf2f(GB[r][1]);                                     \
        float pgv = a2[r] + bf2f(GB[r][2]);                                     \
        float po  = a3[r] + bf2f(GB[r][3]);                                     \
        float ig, fg, g2, og;                                                   \
        if (MODE & 4){ ig=fsig2(pi); fg=fsig2(pf); g2=ftanh2(pgv); og=fsig2(po);}\
        else { ig=pi*0.25f; fg=pf*0.25f; g2=pgv*0.25f; og=po*0.25f; }           \
        float cc = fg*cst[r] + ig*g2;  cst[r] = cc;                             \
        float hn = (MODE & 4) ? og*ftanh2(L2E2*cc) : og*cc;                     \
        u16 hb = f2bf(hn);                                                      \
        hsm[(PB)^1][(hi*4+r)*168 + jj] = hb;                                    \
        if (MODE & 16){                                                         \
          int s_ = (T) & 255;                                                   \
          h1d[(size_t)(prow[r]+s_)*KSTR + jj] = hb;                             \
        }                                                                       \
      }                                                                         \
    }                                                                           \
    if (MODE & 2){ PPREF(GB, ((T)+4)) }                                        \
    else { asm volatile("" : "+v"(GB[0]), "+v"(GB[1]), "+v"(GB[2]), "+v"(GB[3])); } \
    if (MODE & 8){                                                              \
      __builtin_amdgcn_sched_barrier(0);                                        \
      asm volatile("s_waitcnt lgkmcnt(0)");                                     \
      __builtin_amdgcn_sched_barrier(0);                                        \
      __builtin_amdgcn_s_barrier();                                             \
      __builtin_amdgcn_sched_barrier(0);                                        \
    } else {                                                                    \
      asm volatile("s_waitcnt lgkmcnt(0)");                                     \
      __builtin_amdgcn_sched_barrier(0);                                        \
    }                                                                           \
  }

template<int MODE>
__launch_bounds__(640, 2)
__global__ void k_probe(const u16* __restrict__ xg, const u16* __restrict__ Whh,
                        u16* __restrict__ h1d, u16* __restrict__ sink)
{
  __shared__ u16 hsm[2][16*168];
  int tid = threadIdx.x;
  int l = tid & 63, w = tid >> 6;
  int lo = l & 15, hi = l >> 4;
  int jj = w*16 + lo;
  bool jv = (jj < HH);
  int jjc = jv ? jj : 0;

  u16x8 bw[4][5];
  #pragma unroll
  for (int g = 0; g < 4; ++g)
    #pragma unroll
    for (int ks = 0; ks < 5; ++ks)
      bw[g][ks] = *(const u16x8*)(Whh + (size_t)(g*150 + jj)*WK + ks*32 + hi*8);

  for (int i = tid; i < 2*16*168; i += 640) ((u16*)hsm)[i] = 0;
  __syncthreads();

  int prow[4];
  #pragma unroll
  for (int r = 0; r < 4; ++r)
    prow[r] = ((blockIdx.x & 31)*16 + hi*4 + r) * 256;

  float cst[4] = {0.f,0.f,0.f,0.f};
  u16x4 g0[4], g1[4], g2b[4], g3[4];
  PPREF(g0, 0)
  PPREF(g1, 1)
  PPREF(g2b, 2)
  PPREF(g3, 3)

  for (int t = 0; t < 1024; t += 4){
    PSTEP(t, 0, g0)
    PSTEP(t+1, 1, g1)
    PSTEP(t+2, 0, g2b)
    PSTEP(t+3, 1, g3)
  }
  if (tid < 64) sink[blockIdx.x*64 + tid] = f2bf(cst[0]+cst[1]+cst[2]+cst[3]);
}

// ---------------- classifier head (fp32, float4) ----------------
__global__ void k_cls(const float* __restrict__ lastf,
                      const float* __restrict__ W1, const float* __restrict__ b1,
                      const float* __restrict__ W2, const float* __restrict__ b2,
                      float* __restrict__ out)
{
  __shared__ float inb[8][304];
  __shared__ float mid[8][304];
  int r0 = blockIdx.x * 8, tid = threadIdx.x;
  for (int i = tid; i < 8*76; i += 256){
    int r = i / 76, c4 = i - r*76;
    ((f4*)&inb[r][0])[c4] = ((const f4*)(lastf + (size_t)(r0+r)*304))[c4];
  }
  __syncthreads();
  for (int item = tid; item < 2400; item += 256){
    int r = item / 300, c = item - r*300;
    const f4* wr = (const f4*)(W1 + (size_t)c*300);
    const f4* xr = (const f4*)&inb[r][0];
    f4 a0 = {0,0,0,0}, a1 = {0,0,0,0}, a2 = {0,0,0,0};
    for (int k = 0; k < 75; k += 3){
      a0 += xr[k]   * wr[k];
      a1 += xr[k+1] * wr[k+1];
      a2 += xr[k+2] * wr[k+2];
    }
    f4 s4 = a0 + a1 + a2;
    float a = s4[0] + s4[1] + s4[2] + s4[3] + b1[c];
    mid[r][c] = 2.0f * __builtin_amdgcn_rcpf(1.0f + __builtin_amdgcn_exp2f(-L2E2*a)) - 1.0f;
  }
  __syncthreads();
  for (int item = tid; item < 2400; item += 256){
    int r = item / 300, c = item - r*300;
    const f4* wr = (const f4*)(W2 + (size_t)c*300);
    const f4* xr = (const f4*)&mid[r][0];
    f4 a0 = {0,0,0,0}, a1 = {0,0,0,0}, a2 = {0,0,0,0};
    for (int k = 0; k < 75; k += 3){
      a0 += xr[k]   * wr[k];
      a1 += xr[k+1] * wr[k+1];
      a2 += xr[k+2] * wr[k+2];
    }
    f4 s4 = a0 + a1 + a2;
    out[(size_t)(r0+r)*300 + c] = s4[0] + s4[1] + s4[2] + s4[3] + b2[c];
  }
}

extern "C" void kernel_launch(void* const* d_in, const int* in_sizes, int n_in,
                              void* d_out, int out_size, void* d_ws, size_t ws_size,
                              hipStream_t stream)
{
  const int*   x    = (const int*)d_in[0];
  const int*   mask = (const int*)d_in[1];
  const float* emb  = (const float*)d_in[2];
  const float* Wih[4] = {(const float*)d_in[3], (const float*)d_in[6],
                         (const float*)d_in[9], (const float*)d_in[12]};
  const float* Whh[4] = {(const float*)d_in[4], (const float*)d_in[7],
                         (const float*)d_in[10], (const float*)d_in[13]};
  const float* bs[4]  = {(const float*)d_in[5], (const float*)d_in[8],
                         (const float*)d_in[11], (const float*)d_in[14]};
  const float* W1 = (const float*)d_in[15];
  const float* b1 = (const float*)d_in[16];
  const float* W2 = (const float*)d_in[17];
  const float* b2 = (const float*)d_in[18];
  float* out = (float*)d_out;

  char* p = (char*)d_ws;
  auto alloc = [&](size_t bytes){ char* r = p; p += (bytes + 255) & ~(size_t)255; return r; };

  u16 *WihP[4], *WhhP[4];
  for (int i = 0; i < 4; ++i){
    WihP[i] = (u16*)alloc(640*320*2);
    WhhP[i] = (u16*)alloc(640*160*2);
  }
  float* biasP[4];
  for (int i = 0; i < 4; ++i) biasP[i] = (float*)alloc(640*4);
  int* len  = (int*)alloc(1024*4);
  int* perm = (int*)alloc(1024*4);
  float* lastf = (float*)alloc((size_t)1024*304*4);
  u16* embP = (u16*)alloc((size_t)VPAD*KSTR*2);
  u16* tabF = (u16*)alloc((size_t)VPAD*GSTR*2);
  u16* tabB = (u16*)alloc((size_t)VPAD*GSTR*2);
  u16* psink = (u16*)alloc(128*64*2);
  size_t fixed_end = (size_t)(p - (char*)d_ws);

  const size_t per_sample = (size_t)SS*KSTR*2 + 2*(size_t)SS*GSTR*2;  // 778240 B
  int nc = 32;
  const int cands[6] = {1, 2, 4, 8, 16, 32};
  for (int ci = 0; ci < 6; ++ci){
    size_t need = fixed_end + (size_t)(BB / cands[ci]) * per_sample + (1u<<20);
    if (need <= ws_size){ nc = cands[ci]; break; }
  }
  const int Bc = BB / nc;
  const int Mc = Bc * SS;

  u16* h1    = (u16*)alloc((size_t)Mc*KSTR*2);
  u16* gateF = (u16*)alloc((size_t)Mc*GSTR*2);
  u16* gateB = (u16*)alloc((size_t)Mc*GSTR*2);

  (void)hipMemsetAsync(h1, 0, (size_t)Mc*KSTR*2, stream);

  k_len <<<dim3(1024), dim3(256), 0, stream>>>(mask, len);
  k_sort<<<dim3(1),    dim3(1024),0, stream>>>(len, perm);

  PrepW pw;
  for (int i = 0; i < 4; ++i){
    pw.src[i] = Wih[i]; pw.dst[i] = WihP[i];
    pw.R[i] = GG; pw.C[i] = DD; pw.DR[i] = 640; pw.DC[i] = KSTR;
    pw.src[4+i] = Whh[i]; pw.dst[4+i] = WhhP[i];
    pw.R[4+i] = GG; pw.C[4+i] = HH; pw.DR[4+i] = 640; pw.DC[4+i] = WK;
  }
  k_prepw<<<dim3(800, 8), dim3(256), 0, stream>>>(pw);

  PrepB pb;
  for (int i = 0; i < 4; ++i){ pb.src[i] = bs[i]; pb.dst[i] = biasP[i]; }
  k_prepb<<<dim3(3, 4), dim3(256), 0, stream>>>(pb);

  k_prepemb<<<dim3((VPAD*KSTR + 255)/256), dim3(256), 0, stream>>>(emb, embP);

  k_gemm<<<dim3(VPAD/128, 2, 2), dim3(512), 0, stream>>>(embP, WihP[0], WihP[1],
                                                         biasP[0], biasP[1], tabF, tabB);

  k_recM<<<dim3(Bc/16, 2, 1), dim3(640), 0, stream>>>(gateF, gateB, tabF, tabB,
                                                      WhhP[0], WhhP[1], WhhP[2], WhhP[3],
                                                      len, perm, x, h1, lastf,
                                                      0, 0, /*mode0=*/0);
  k_gemm<<<dim3(Mc/128, 2, 2), dim3(512), 0, stream>>>(h1, WihP[2], WihP[3],
                                                       biasP[2], biasP[3], gateF, gateB);
  for (int c = 0; c < nc; ++c){
    if (c + 1 < nc){
      k_recM<<<dim3(Bc/16, 2, 2), dim3(640), 0, stream>>>(gateF, gateB, tabF, tabB,
                                                          WhhP[0], WhhP[1], WhhP[2], WhhP[3],
                                                          len, perm, x, h1, lastf,
                                                          c*Bc, (c+1)*Bc, /*mode0=*/1);
      k_gemm<<<dim3(Mc/128, 2, 2), dim3(512), 0, stream>>>(h1, WihP[2], WihP[3],
                                                           biasP[2], biasP[3], gateF, gateB);
    } else {
      k_recM<<<dim3(Bc/16, 2, 1), dim3(640), 0, stream>>>(gateF, gateB, tabF, tabB,
                                                          WhhP[0], WhhP[1], WhhP[2], WhhP[3],
                                                          len, perm, x, h1, lastf,
                                                          c*Bc, 0, /*mode0=*/1);
    }
  }

  k_cls<<<dim3(128), dim3(256), 0, stream>>>(lastf, W1, b1, W2, b2, out);

  // ---- quantitative probes (1024 steps; all 5 should occupy the top-5 slots) ----
  k_probe<31><<<dim3(128), dim3(640), 0, stream>>>(gateF, WhhP[2], h1, psink);  // full
  k_probe<29><<<dim3(128), dim3(640), 0, stream>>>(gateF, WhhP[2], h1, psink);  // -loads
  k_probe<15><<<dim3(128), dim3(640), 0, stream>>>(gateF, WhhP[2], h1, psink);  // -stores
  k_probe<13><<<dim3(128), dim3(640), 0, stream>>>(gateF, WhhP[2], h1, psink);  // -loads-stores
  k_probe< 9><<<dim3(128), dim3(640), 0, stream>>>(gateF, WhhP[2], h1, psink);  // MFMA+barrier floor
}